// Round 6
// baseline (398.702 us; speedup 1.0000x reference)
//
#include <hip/hip_runtime.h>
#include <hip/hip_bf16.h>
#include <math.h>

#define D 128
#define NUM_GRAPHS 64
#define CHUNK 16384         // edges per binning block
#define BUCK_SH 10          // bucket = col >> 10  (1024 nodes per bucket)
#define BUCK_N 1024

typedef __bf16 bf16x8 __attribute__((ext_vector_type(8)));
typedef __bf16 bf16x2 __attribute__((ext_vector_type(2)));
typedef float f32x4 __attribute__((ext_vector_type(4)));

// ---------------- generic scan helpers (for the bucket-chunk table) ----------------
__global__ void k_scan1(const int* __restrict__ in, int* __restrict__ outv,
                        int* __restrict__ bsum, int N) {
    __shared__ int lds[256];
    int t = threadIdx.x;
    int base = blockIdx.x * 1024 + t * 4;
    int v[4]; int local = 0;
#pragma unroll
    for (int j = 0; j < 4; j++) { v[j] = (base + j < N) ? in[base + j] : 0; local += v[j]; }
    lds[t] = local;
    __syncthreads();
    for (int off = 1; off < 256; off <<= 1) {
        int x = (t >= off) ? lds[t - off] : 0;
        __syncthreads();
        lds[t] += x;
        __syncthreads();
    }
    int excl = lds[t] - local;
    if (t == 255) bsum[blockIdx.x] = lds[255];
    int run = excl;
#pragma unroll
    for (int j = 0; j < 4; j++) { if (base + j < N) outv[base + j] = run; run += v[j]; }
}

__global__ void k_scan2(int* __restrict__ bsum, int nb) {
    __shared__ int lds[256];
    int t = threadIdx.x;
    int v = (t < nb) ? bsum[t] : 0;
    lds[t] = v;
    __syncthreads();
    for (int off = 1; off < 256; off <<= 1) {
        int x = (t >= off) ? lds[t - off] : 0;
        __syncthreads();
        lds[t] += x;
        __syncthreads();
    }
    if (t < nb) bsum[t] = lds[t] - v;
}

// ---------------- CSR build: two-level counting sort ----------------
// pass 1: per-chunk histogram over coarse buckets (col>>10)
__global__ void k_hist(const int* __restrict__ col, int* __restrict__ hist,
                       int nbuck, int nchunk, int E) {
    __shared__ int h[128];
    int tid = threadIdx.x;
    if (tid < 128) h[tid] = 0;
    __syncthreads();
    int base = blockIdx.x * CHUNK;
    for (int i = tid; i < CHUNK; i += 256) {
        int e = base + i;
        if (e < E) atomicAdd(&h[col[e] >> BUCK_SH], 1);
    }
    __syncthreads();
    for (int b = tid; b < nbuck; b += 256) hist[b * nchunk + blockIdx.x] = h[b];
}

// pass 2: bin edges into bucket-contiguous packed (src | (col&1023)<<17) records
__global__ void k_bin(const int* __restrict__ ei, const int* __restrict__ histS,
                      const int* __restrict__ bsum2, int* __restrict__ bbuf,
                      int nbuck, int nchunk, int E) {
    __shared__ int cur[128];
    int tid = threadIdx.x;
    for (int b = tid; b < nbuck; b += 256) {
        int idx = b * nchunk + blockIdx.x;
        cur[b] = histS[idx] + bsum2[idx >> 10];
    }
    __syncthreads();
    int base = blockIdx.x * CHUNK;
    for (int i = tid; i < CHUNK; i += 256) {
        int e = base + i;
        if (e < E) {
            int r = ei[e], c = ei[E + e];
            int pos = atomicAdd(&cur[c >> BUCK_SH], 1);
            bbuf[pos] = r | ((c & (BUCK_N - 1)) << 17);   // src fits 17 bits (N < 131072)
        }
    }
}

// pass 3: per-bucket exact CSR for 1024 nodes: LDS histogram + LDS scan + LDS
// cursors. Writes cnt/offs/dis per node and esrc (src only) — no global atomics.
__global__ void k_place(const int* __restrict__ bbuf, const int* __restrict__ histS,
                        const int* __restrict__ bsum2, int* __restrict__ esrc,
                        int* __restrict__ cnt, int* __restrict__ offs,
                        float* __restrict__ dis,
                        int nbuck, int nchunk, int N, int E) {
    __shared__ int h[BUCK_N];
    __shared__ int cur[BUCK_N];
    __shared__ int tsum[256];
    int b = blockIdx.x, tid = threadIdx.x;
    int i0 = b * nchunk;
    int start = histS[i0] + bsum2[i0 >> 10];
    int end = E;
    if (b + 1 < nbuck) { int i1 = (b + 1) * nchunk; end = histS[i1] + bsum2[i1 >> 10]; }
#pragma unroll
    for (int j = 0; j < 4; j++) h[tid * 4 + j] = 0;
    __syncthreads();
    for (int i = start + tid; i < end; i += 256) atomicAdd(&h[(bbuf[i] >> 17) & (BUCK_N - 1)], 1);
    __syncthreads();
    // exclusive scan of h[0..1023]: 4 elems per thread
    int v[4]; int local = 0;
#pragma unroll
    for (int j = 0; j < 4; j++) { v[j] = h[tid * 4 + j]; local += v[j]; }
    tsum[tid] = local;
    __syncthreads();
    for (int off = 1; off < 256; off <<= 1) {
        int xv = (tid >= off) ? tsum[tid - off] : 0;
        __syncthreads();
        tsum[tid] += xv;
        __syncthreads();
    }
    int run = start + tsum[tid] - local;
#pragma unroll
    for (int j = 0; j < 4; j++) {
        int lc = tid * 4 + j;
        cur[lc] = run;
        int c = b * BUCK_N + lc;
        if (c < N) {
            cnt[c]  = v[j];
            offs[c] = run;
            dis[c]  = rsqrtf(1.0f + (float)v[j]);   // deg includes self-loop
        }
        run += v[j];
    }
    __syncthreads();
    for (int i = start + tid; i < end; i += 256) {
        int p = bbuf[i];
        int pos = atomicAdd(&cur[(p >> 17) & (BUCK_N - 1)], 1);
        esrc[pos] = p & 0x1FFFF;
    }
}

// ---------------- W -> bf16 B-fragment pack (both weights in one launch) ----------------
__global__ void k_prepW(const float* __restrict__ Wa, const float* __restrict__ Wb,
                        __bf16* __restrict__ WfA, __bf16* __restrict__ WfB) {
    int gid = blockIdx.x * 256 + threadIdx.x;   // 0..32767
    const float* W = (gid < 16384) ? Wa : Wb;
    __bf16* Wf = (gid < 16384) ? WfA : WfB;
    int idx = gid & 16383;
    int j = idx & 7, lane = (idx >> 3) & 63, kc = (idx >> 9) & 3, ft = idx >> 11;
    int k = kc * 32 + (lane >> 4) * 8 + j;
    int f = ft * 16 + (lane & 15);
    Wf[idx] = (__bf16)W[k * D + f];
}

// ---------------- MFMA GEMM: Y[N,128](bf16) = dis .* (X[N,128] @ W) ----------------
template <typename T>
__launch_bounds__(256)
__global__ void k_gemm(const T* __restrict__ X, const __bf16* __restrict__ Wfrag,
                       const float* __restrict__ dis, __bf16* __restrict__ Y, int N) {
    int tid = threadIdx.x;
    int w = tid >> 6, lane = tid & 63;
    int quad = lane >> 4, m = lane & 15;
    int nodeA = blockIdx.x * 64 + w * 16 + m;
    if (nodeA >= N) nodeA = N - 1;

    bf16x8 a[4];
#pragma unroll
    for (int kc = 0; kc < 4; kc++) {
        int kb = kc * 32 + quad * 8;
        if constexpr (sizeof(T) == 4) {
            f32x4 x0 = *(const f32x4*)(X + (size_t)nodeA * D + kb);
            f32x4 x1 = *(const f32x4*)(X + (size_t)nodeA * D + kb + 4);
#pragma unroll
            for (int j = 0; j < 4; j++) { a[kc][j] = (__bf16)x0[j]; a[kc][4 + j] = (__bf16)x1[j]; }
        } else {
            a[kc] = *(const bf16x8*)(X + (size_t)nodeA * D + kb);
        }
    }

    f32x4 d[8];
#pragma unroll
    for (int ft = 0; ft < 8; ft++) {
        d[ft] = (f32x4){0.f, 0.f, 0.f, 0.f};
#pragma unroll
        for (int kc = 0; kc < 4; kc++) {
            bf16x8 b = *(const bf16x8*)(Wfrag + (((ft << 2) | kc) * 64 + lane) * 8);
            d[ft] = __builtin_amdgcn_mfma_f32_16x16x32_bf16(a[kc], b, d[ft], 0, 0, 0);
        }
    }

#pragma unroll
    for (int r = 0; r < 4; r++) {
        int node = blockIdx.x * 64 + w * 16 + quad * 4 + r;
        if (node < N) {
            float dv = dis[node];
#pragma unroll
            for (int ft = 0; ft < 8; ft++)
                Y[(size_t)node * D + ft * 16 + m] = (__bf16)(d[ft][r] * dv);
        }
    }
}

// ---------------- CSR aggregation + bias + leaky ReLU (bf16 in/out) ----------------
__launch_bounds__(256)
__global__ void k_agg(const __bf16* __restrict__ Hs, __bf16* __restrict__ O,
                      const int* __restrict__ offs, const int* __restrict__ cnt,
                      const float* __restrict__ dis, const int* __restrict__ esrc,
                      const float* __restrict__ bias, int N) {
    int node = (blockIdx.x * 256 + threadIdx.x) >> 6;
    int lane = threadIdx.x & 63;
    if (node >= N) return;
    int start = offs[node];
    int len = cnt[node];
    float di = dis[node];
    bf16x2 h = *(const bf16x2*)(Hs + (size_t)node * D + lane * 2);
    float acc0 = (float)h[0];            // self-loop term (already dis-scaled)
    float acc1 = (float)h[1];

    for (int k0 = 0; k0 < len; k0 += 64) {
        int mm = len - k0; if (mm > 64) mm = 64;
        int ep = esrc[start + k0 + (lane < mm ? lane : 0)];
        int j = 0;
        for (; j + 16 <= mm; j += 16) {
            int s[16]; bf16x2 hv[16];
#pragma unroll
            for (int u = 0; u < 16; u++) s[u] = __shfl(ep, j + u);
#pragma unroll
            for (int u = 0; u < 16; u++) hv[u] = *(const bf16x2*)(Hs + (size_t)s[u] * D + lane * 2);
#pragma unroll
            for (int u = 0; u < 16; u++) { acc0 += (float)hv[u][0]; acc1 += (float)hv[u][1]; }
        }
        for (; j + 4 <= mm; j += 4) {
            int s[4]; bf16x2 hv[4];
#pragma unroll
            for (int u = 0; u < 4; u++) s[u] = __shfl(ep, j + u);
#pragma unroll
            for (int u = 0; u < 4; u++) hv[u] = *(const bf16x2*)(Hs + (size_t)s[u] * D + lane * 2);
#pragma unroll
            for (int u = 0; u < 4; u++) { acc0 += (float)hv[u][0]; acc1 += (float)hv[u][1]; }
        }
        for (; j < mm; j++) {
            int s = __shfl(ep, j);
            bf16x2 hv = *(const bf16x2*)(Hs + (size_t)s * D + lane * 2);
            acc0 += (float)hv[0]; acc1 += (float)hv[1];
        }
    }

    acc0 = acc0 * di + bias[lane * 2];
    acc1 = acc1 * di + bias[lane * 2 + 1];
    acc0 = acc0 >= 0.f ? acc0 : 0.01f * acc0;
    acc1 = acc1 >= 0.f ? acc1 : 0.01f * acc1;
    bf16x2 o; o[0] = (__bf16)acc0; o[1] = (__bf16)acc1;
    *(bf16x2*)(O + (size_t)node * D + lane * 2) = o;
}

// ---------------- pooling (bf16 in, fp32 accum) ----------------
__global__ void k_pool(const __bf16* __restrict__ H, const int* __restrict__ batch,
                       float* __restrict__ pooled, float* __restrict__ gcnt, int N) {
    int f = threadIdx.x;                 // 0..127
    int n0 = blockIdx.x * 128;
    if (n0 >= N) return;
    int n1 = min(n0 + 128, N);
    int cur = batch[n0];
    float acc = 0.f; int run = 0;
    for (int n = n0; n < n1; n++) {
        int g = batch[n];                // uniform across block -> no divergence
        if (g != cur) {
            atomicAdd(&pooled[cur * D + f], acc);
            if (f == 0) atomicAdd(&gcnt[cur], (float)run);
            acc = 0.f; run = 0; cur = g;
        }
        acc += (float)H[(size_t)n * D + f];
        run++;
    }
    atomicAdd(&pooled[cur * D + f], acc);
    if (f == 0) atomicAdd(&gcnt[cur], (float)run);
}

// ---------------- final FC ----------------
__global__ void k_fc(const float* __restrict__ pooled, const float* __restrict__ gcnt,
                     const float* __restrict__ fcW, const float* __restrict__ fcb,
                     float* __restrict__ out) {
    __shared__ float red[128];
    int g = blockIdx.x;
    int f = threadIdx.x;
    red[f] = pooled[g * D + f] * fcW[f];
    __syncthreads();
    for (int s = 64; s > 0; s >>= 1) {
        if (f < s) red[f] += red[f + s];
        __syncthreads();
    }
    if (f == 0) out[g] = red[0] / fmaxf(gcnt[g], 1.0f) + fcb[0];
}

extern "C" void kernel_launch(void* const* d_in, const int* in_sizes, int n_in,
                              void* d_out, int out_size, void* d_ws, size_t ws_size,
                              hipStream_t stream) {
    const float* x    = (const float*)d_in[0];
    const int*   ei   = (const int*)d_in[1];
    const int*   batch= (const int*)d_in[2];
    const float* W1   = (const float*)d_in[3];
    const float* b1   = (const float*)d_in[4];
    const float* W2   = (const float*)d_in[5];
    const float* b2   = (const float*)d_in[6];
    const float* fcW  = (const float*)d_in[7];
    const float* fcb  = (const float*)d_in[8];
    float* out = (float*)d_out;

    int N = in_sizes[0] / D;
    int E = in_sizes[1] / 2;

    int NBUCK  = (N + BUCK_N - 1) >> BUCK_SH;  // 98 for N=100000 (<=128)
    int NCHUNK = (E + CHUNK - 1) / CHUNK;      // 98 for E=1.6M
    int M = NBUCK * NCHUNK;                    // 9604
    int mb = (M + 1023) / 1024;                // 10 (<=256)

    char* p = (char*)d_ws;
    auto alloc = [&](size_t bytes) { char* r = p; p += (bytes + 255) & ~(size_t)255; return r; };
    int*    cnt    = (int*)   alloc((size_t)N * 4);
    int*    offs   = (int*)   alloc((size_t)N * 4);
    int*    bsum2  = (int*)   alloc(256 * 4);
    float*  dis    = (float*) alloc((size_t)N * 4);
    int*    hist   = (int*)   alloc((size_t)M * 4);
    int*    histS  = (int*)   alloc((size_t)M * 4);
    int*    bbuf   = (int*)   alloc((size_t)E * 4);
    int*    esrc   = (int*)   alloc((size_t)E * 4);
    __bf16* bufA   = (__bf16*)alloc((size_t)N * D * 2);
    __bf16* bufB   = (__bf16*)alloc((size_t)N * D * 2);
    __bf16* Wf1    = (__bf16*)alloc((size_t)D * D * 2);
    __bf16* Wf2    = (__bf16*)alloc((size_t)D * D * 2);
    float*  pooled = (float*) alloc((size_t)NUM_GRAPHS * D * 4);
    float*  gcnt   = (float*) alloc((size_t)NUM_GRAPHS * 4);

    hipMemsetAsync(pooled, 0, (size_t)NUM_GRAPHS * D * 4, stream);
    hipMemsetAsync(gcnt, 0, (size_t)NUM_GRAPHS * 4, stream);

    // CSR build: hist -> scan -> bin -> per-bucket place (all-LDS cursors)
    k_hist <<<NCHUNK, 256, 0, stream>>>(ei + E, hist, NBUCK, NCHUNK, E);
    k_scan1<<<mb, 256, 0, stream>>>(hist, histS, bsum2, M);
    k_scan2<<<1, 256, 0, stream>>>(bsum2, mb);
    k_bin  <<<NCHUNK, 256, 0, stream>>>(ei, histS, bsum2, bbuf, NBUCK, NCHUNK, E);
    k_place<<<NBUCK, 256, 0, stream>>>(bbuf, histS, bsum2, esrc, cnt, offs, dis,
                                       NBUCK, NCHUNK, N, E);

    k_prepW<<<128, 256, 0, stream>>>(W1, W2, Wf1, Wf2);

    int gblocks = (N + 63) / 64;

    // layer 1 (GEMM output prescaled by dis)
    k_gemm<float><<<gblocks, 256, 0, stream>>>(x, Wf1, dis, bufA, N);
    k_agg<<<(N + 3) / 4, 256, 0, stream>>>(bufA, bufB, offs, cnt, dis, esrc, b1, N);
    // layer 2
    k_gemm<__bf16><<<gblocks, 256, 0, stream>>>(bufB, Wf2, dis, bufA, N);
    k_agg<<<(N + 3) / 4, 256, 0, stream>>>(bufA, bufB, offs, cnt, dis, esrc, b2, N);
    // pool + fc
    k_pool<<<(N + 127) / 128, 128, 0, stream>>>(bufB, batch, pooled, gcnt, N);
    k_fc<<<NUM_GRAPHS, 128, 0, stream>>>(pooled, gcnt, fcW, fcb, out);
}

// Round 7
// 380.802 us; speedup vs baseline: 1.0470x; 1.0470x over previous
//
#include <hip/hip_runtime.h>
#include <hip/hip_bf16.h>
#include <math.h>

#define D 128
#define NUM_GRAPHS 64
#define CHUNK 8192          // edges per binning block
#define BUCK_SH 8           // bucket = col >> 8  (256 nodes per bucket)
#define BUCK_N 256

typedef __bf16 bf16x8 __attribute__((ext_vector_type(8)));
typedef __bf16 bf16x2 __attribute__((ext_vector_type(2)));
typedef float f32x4 __attribute__((ext_vector_type(4)));

// ---------------- generic scan helpers (for the bucket-chunk table) ----------------
__global__ void k_scan1(const int* __restrict__ in, int* __restrict__ outv,
                        int* __restrict__ bsum, int N) {
    __shared__ int lds[256];
    int t = threadIdx.x;
    int base = blockIdx.x * 1024 + t * 4;
    int v[4]; int local = 0;
#pragma unroll
    for (int j = 0; j < 4; j++) { v[j] = (base + j < N) ? in[base + j] : 0; local += v[j]; }
    lds[t] = local;
    __syncthreads();
    for (int off = 1; off < 256; off <<= 1) {
        int x = (t >= off) ? lds[t - off] : 0;
        __syncthreads();
        lds[t] += x;
        __syncthreads();
    }
    int excl = lds[t] - local;
    if (t == 255) bsum[blockIdx.x] = lds[255];
    int run = excl;
#pragma unroll
    for (int j = 0; j < 4; j++) { if (base + j < N) outv[base + j] = run; run += v[j]; }
}

__global__ void k_scan2(int* __restrict__ bsum, int nb) {
    __shared__ int lds[256];
    int t = threadIdx.x;
    int v = (t < nb) ? bsum[t] : 0;
    lds[t] = v;
    __syncthreads();
    for (int off = 1; off < 256; off <<= 1) {
        int x = (t >= off) ? lds[t - off] : 0;
        __syncthreads();
        lds[t] += x;
        __syncthreads();
    }
    if (t < nb) bsum[t] = lds[t] - v;
}

// ---------------- CSR build: two-level counting sort (R5 config: 256-node buckets) ----------------
// pass 1: per-chunk histogram over coarse buckets (col>>8)
__global__ void k_hist(const int* __restrict__ col, int* __restrict__ hist,
                       int nbuck, int nchunk, int E) {
    __shared__ int h[512];
    int tid = threadIdx.x;
    for (int b = tid; b < nbuck; b += 256) h[b] = 0;
    __syncthreads();
    int base = blockIdx.x * CHUNK;
    for (int i = tid; i < CHUNK; i += 256) {
        int e = base + i;
        if (e < E) atomicAdd(&h[col[e] >> BUCK_SH], 1);
    }
    __syncthreads();
    for (int b = tid; b < nbuck; b += 256) hist[b * nchunk + blockIdx.x] = h[b];
}

// pass 2: bin edges into bucket-contiguous packed (src | (col&255)<<17) records
__global__ void k_bin(const int* __restrict__ ei, const int* __restrict__ histS,
                      const int* __restrict__ bsum2, int* __restrict__ bbuf,
                      int nbuck, int nchunk, int E) {
    __shared__ int cur[512];
    int tid = threadIdx.x;
    for (int b = tid; b < nbuck; b += 256) {
        int idx = b * nchunk + blockIdx.x;
        cur[b] = histS[idx] + bsum2[idx >> 10];
    }
    __syncthreads();
    int base = blockIdx.x * CHUNK;
    for (int i = tid; i < CHUNK; i += 256) {
        int e = base + i;
        if (e < E) {
            int r = ei[e], c = ei[E + e];
            int pos = atomicAdd(&cur[c >> BUCK_SH], 1);
            bbuf[pos] = r | ((c & (BUCK_N - 1)) << 17);   // src fits 17 bits (N < 131072)
        }
    }
}

// pass 3: per-bucket exact CSR: LDS histogram + LDS scan + LDS cursors.
// Writes cnt/offs/dis per node and esrc (src only) — no global atomics.
__global__ void k_place(const int* __restrict__ bbuf, const int* __restrict__ histS,
                        const int* __restrict__ bsum2, int* __restrict__ esrc,
                        int* __restrict__ cnt, int* __restrict__ offs,
                        float* __restrict__ dis,
                        int nbuck, int nchunk, int N, int E) {
    __shared__ int h[256];
    __shared__ int sc[256];
    __shared__ int cur[256];
    int b = blockIdx.x, tid = threadIdx.x;
    int i0 = b * nchunk;
    int start = histS[i0] + bsum2[i0 >> 10];
    int end = E;
    if (b + 1 < nbuck) { int i1 = (b + 1) * nchunk; end = histS[i1] + bsum2[i1 >> 10]; }
    h[tid] = 0;
    __syncthreads();
    for (int i = start + tid; i < end; i += 256) atomicAdd(&h[(bbuf[i] >> 17) & 255], 1);
    __syncthreads();
    int local = h[tid];
    sc[tid] = local;
    __syncthreads();
    for (int off = 1; off < 256; off <<= 1) {
        int xv = (tid >= off) ? sc[tid - off] : 0;
        __syncthreads();
        sc[tid] += xv;
        __syncthreads();
    }
    int excl = sc[tid] - local;
    cur[tid] = start + excl;
    int c = b * 256 + tid;
    if (c < N) {
        cnt[c]  = local;
        offs[c] = start + excl;
        dis[c]  = rsqrtf(1.0f + (float)local);   // deg includes self-loop
    }
    __syncthreads();
    for (int i = start + tid; i < end; i += 256) {
        int p = bbuf[i];
        int pos = atomicAdd(&cur[(p >> 17) & 255], 1);
        esrc[pos] = p & 0x1FFFF;
    }
}

// ---------------- W -> bf16 B-fragment pack (both weights; also zeroes pooled/gcnt) ----------------
__global__ void k_prepW(const float* __restrict__ Wa, const float* __restrict__ Wb,
                        __bf16* __restrict__ WfA, __bf16* __restrict__ WfB,
                        float* __restrict__ pooled, float* __restrict__ gcnt) {
    int gid = blockIdx.x * 256 + threadIdx.x;   // 0..32767
    if (gid < NUM_GRAPHS * D) pooled[gid] = 0.f;
    if (gid < NUM_GRAPHS) gcnt[gid] = 0.f;
    const float* W = (gid < 16384) ? Wa : Wb;
    __bf16* Wf = (gid < 16384) ? WfA : WfB;
    int idx = gid & 16383;
    int j = idx & 7, lane = (idx >> 3) & 63, kc = (idx >> 9) & 3, ft = idx >> 11;
    int k = kc * 32 + (lane >> 4) * 8 + j;
    int f = ft * 16 + (lane & 15);
    Wf[idx] = (__bf16)W[k * D + f];
}

// ---------------- MFMA GEMM: Y[N,128](bf16) = dis .* (X[N,128] @ W) ----------------
template <typename T>
__launch_bounds__(256)
__global__ void k_gemm(const T* __restrict__ X, const __bf16* __restrict__ Wfrag,
                       const float* __restrict__ dis, __bf16* __restrict__ Y, int N) {
    int tid = threadIdx.x;
    int w = tid >> 6, lane = tid & 63;
    int quad = lane >> 4, m = lane & 15;
    int nodeA = blockIdx.x * 64 + w * 16 + m;
    if (nodeA >= N) nodeA = N - 1;

    bf16x8 a[4];
#pragma unroll
    for (int kc = 0; kc < 4; kc++) {
        int kb = kc * 32 + quad * 8;
        if constexpr (sizeof(T) == 4) {
            f32x4 x0 = *(const f32x4*)(X + (size_t)nodeA * D + kb);
            f32x4 x1 = *(const f32x4*)(X + (size_t)nodeA * D + kb + 4);
#pragma unroll
            for (int j = 0; j < 4; j++) { a[kc][j] = (__bf16)x0[j]; a[kc][4 + j] = (__bf16)x1[j]; }
        } else {
            a[kc] = *(const bf16x8*)(X + (size_t)nodeA * D + kb);
        }
    }

    f32x4 d[8];
#pragma unroll
    for (int ft = 0; ft < 8; ft++) {
        d[ft] = (f32x4){0.f, 0.f, 0.f, 0.f};
#pragma unroll
        for (int kc = 0; kc < 4; kc++) {
            bf16x8 b = *(const bf16x8*)(Wfrag + (((ft << 2) | kc) * 64 + lane) * 8);
            d[ft] = __builtin_amdgcn_mfma_f32_16x16x32_bf16(a[kc], b, d[ft], 0, 0, 0);
        }
    }

#pragma unroll
    for (int r = 0; r < 4; r++) {
        int node = blockIdx.x * 64 + w * 16 + quad * 4 + r;
        if (node < N) {
            float dv = dis[node];
#pragma unroll
            for (int ft = 0; ft < 8; ft++)
                Y[(size_t)node * D + ft * 16 + m] = (__bf16)(d[ft][r] * dv);
        }
    }
}

// ---------------- CSR aggregation + bias + leaky ReLU (bf16 in/out) ----------------
// Hs is prescaled by dis -> no per-edge weight. One wave per node; lane owns
// feats (2*lane, 2*lane+1). Edge meta: nontemporal coalesced load + shfl
// broadcast; output store nontemporal (both streaming — protect Hs in L2).
__launch_bounds__(256)
__global__ void k_agg(const __bf16* __restrict__ Hs, __bf16* __restrict__ O,
                      const int* __restrict__ offs, const int* __restrict__ cnt,
                      const float* __restrict__ dis, const int* __restrict__ esrc,
                      const float* __restrict__ bias, int N) {
    int node = (blockIdx.x * 256 + threadIdx.x) >> 6;
    int lane = threadIdx.x & 63;
    if (node >= N) return;
    int start = offs[node];
    int len = cnt[node];
    float di = dis[node];
    bf16x2 h = *(const bf16x2*)(Hs + (size_t)node * D + lane * 2);
    float acc0 = (float)h[0];            // self-loop term (already dis-scaled)
    float acc1 = (float)h[1];

    for (int k0 = 0; k0 < len; k0 += 64) {
        int mm = len - k0; if (mm > 64) mm = 64;
        int ep = __builtin_nontemporal_load(&esrc[start + k0 + (lane < mm ? lane : 0)]);
        int j = 0;
        for (; j + 16 <= mm; j += 16) {
            int s[16]; bf16x2 hv[16];
#pragma unroll
            for (int u = 0; u < 16; u++) s[u] = __shfl(ep, j + u);
#pragma unroll
            for (int u = 0; u < 16; u++) hv[u] = *(const bf16x2*)(Hs + (size_t)s[u] * D + lane * 2);
#pragma unroll
            for (int u = 0; u < 16; u++) { acc0 += (float)hv[u][0]; acc1 += (float)hv[u][1]; }
        }
        for (; j + 4 <= mm; j += 4) {
            int s[4]; bf16x2 hv[4];
#pragma unroll
            for (int u = 0; u < 4; u++) s[u] = __shfl(ep, j + u);
#pragma unroll
            for (int u = 0; u < 4; u++) hv[u] = *(const bf16x2*)(Hs + (size_t)s[u] * D + lane * 2);
#pragma unroll
            for (int u = 0; u < 4; u++) { acc0 += (float)hv[u][0]; acc1 += (float)hv[u][1]; }
        }
        for (; j < mm; j++) {
            int s = __shfl(ep, j);
            bf16x2 hv = *(const bf16x2*)(Hs + (size_t)s * D + lane * 2);
            acc0 += (float)hv[0]; acc1 += (float)hv[1];
        }
    }

    acc0 = acc0 * di + bias[lane * 2];
    acc1 = acc1 * di + bias[lane * 2 + 1];
    acc0 = acc0 >= 0.f ? acc0 : 0.01f * acc0;
    acc1 = acc1 >= 0.f ? acc1 : 0.01f * acc1;
    bf16x2 o; o[0] = (__bf16)acc0; o[1] = (__bf16)acc1;
    __builtin_nontemporal_store(o, (bf16x2*)(O + (size_t)node * D + lane * 2));
}

// ---------------- pooling (bf16 in, fp32 accum) ----------------
__global__ void k_pool(const __bf16* __restrict__ H, const int* __restrict__ batch,
                       float* __restrict__ pooled, float* __restrict__ gcnt, int N) {
    int f = threadIdx.x;                 // 0..127
    int n0 = blockIdx.x * 128;
    if (n0 >= N) return;
    int n1 = min(n0 + 128, N);
    int cur = batch[n0];
    float acc = 0.f; int run = 0;
    for (int n = n0; n < n1; n++) {
        int g = batch[n];                // uniform across block -> no divergence
        if (g != cur) {
            atomicAdd(&pooled[cur * D + f], acc);
            if (f == 0) atomicAdd(&gcnt[cur], (float)run);
            acc = 0.f; run = 0; cur = g;
        }
        acc += (float)H[(size_t)n * D + f];
        run++;
    }
    atomicAdd(&pooled[cur * D + f], acc);
    if (f == 0) atomicAdd(&gcnt[cur], (float)run);
}

// ---------------- final FC ----------------
__global__ void k_fc(const float* __restrict__ pooled, const float* __restrict__ gcnt,
                     const float* __restrict__ fcW, const float* __restrict__ fcb,
                     float* __restrict__ out) {
    __shared__ float red[128];
    int g = blockIdx.x;
    int f = threadIdx.x;
    red[f] = pooled[g * D + f] * fcW[f];
    __syncthreads();
    for (int s = 64; s > 0; s >>= 1) {
        if (f < s) red[f] += red[f + s];
        __syncthreads();
    }
    if (f == 0) out[g] = red[0] / fmaxf(gcnt[g], 1.0f) + fcb[0];
}

extern "C" void kernel_launch(void* const* d_in, const int* in_sizes, int n_in,
                              void* d_out, int out_size, void* d_ws, size_t ws_size,
                              hipStream_t stream) {
    const float* x    = (const float*)d_in[0];
    const int*   ei   = (const int*)d_in[1];
    const int*   batch= (const int*)d_in[2];
    const float* W1   = (const float*)d_in[3];
    const float* b1   = (const float*)d_in[4];
    const float* W2   = (const float*)d_in[5];
    const float* b2   = (const float*)d_in[6];
    const float* fcW  = (const float*)d_in[7];
    const float* fcb  = (const float*)d_in[8];
    float* out = (float*)d_out;

    int N = in_sizes[0] / D;
    int E = in_sizes[1] / 2;

    int NBUCK  = (N + BUCK_N - 1) >> BUCK_SH;  // 391 for N=100000 (<=512)
    int NCHUNK = (E + CHUNK - 1) / CHUNK;      // 196 for E=1.6M
    int M = NBUCK * NCHUNK;                    // 76,636
    int mb = (M + 1023) / 1024;                // 75 (<=256)

    char* p = (char*)d_ws;
    auto alloc = [&](size_t bytes) { char* r = p; p += (bytes + 255) & ~(size_t)255; return r; };
    int*    cnt    = (int*)   alloc((size_t)N * 4);
    int*    offs   = (int*)   alloc((size_t)N * 4);
    int*    bsum2  = (int*)   alloc(256 * 4);
    float*  dis    = (float*) alloc((size_t)N * 4);
    int*    hist   = (int*)   alloc((size_t)M * 4);
    int*    histS  = (int*)   alloc((size_t)M * 4);
    int*    bbuf   = (int*)   alloc((size_t)E * 4);
    int*    esrc   = (int*)   alloc((size_t)E * 4);
    __bf16* bufA   = (__bf16*)alloc((size_t)N * D * 2);
    __bf16* bufB   = (__bf16*)alloc((size_t)N * D * 2);
    __bf16* Wf1    = (__bf16*)alloc((size_t)D * D * 2);
    __bf16* Wf2    = (__bf16*)alloc((size_t)D * D * 2);
    float*  pooled = (float*) alloc((size_t)NUM_GRAPHS * D * 4);
    float*  gcnt   = (float*) alloc((size_t)NUM_GRAPHS * 4);

    // CSR build: hist -> scan -> bin -> per-bucket place (all-LDS cursors)
    k_hist <<<NCHUNK, 256, 0, stream>>>(ei + E, hist, NBUCK, NCHUNK, E);
    k_scan1<<<mb, 256, 0, stream>>>(hist, histS, bsum2, M);
    k_scan2<<<1, 256, 0, stream>>>(bsum2, mb);
    k_bin  <<<NCHUNK, 256, 0, stream>>>(ei, histS, bsum2, bbuf, NBUCK, NCHUNK, E);
    k_place<<<NBUCK, 256, 0, stream>>>(bbuf, histS, bsum2, esrc, cnt, offs, dis,
                                       NBUCK, NCHUNK, N, E);

    k_prepW<<<128, 256, 0, stream>>>(W1, W2, Wf1, Wf2, pooled, gcnt);

    int gblocks = (N + 63) / 64;

    // layer 1 (GEMM output prescaled by dis)
    k_gemm<float><<<gblocks, 256, 0, stream>>>(x, Wf1, dis, bufA, N);
    k_agg<<<(N + 3) / 4, 256, 0, stream>>>(bufA, bufB, offs, cnt, dis, esrc, b1, N);
    // layer 2
    k_gemm<__bf16><<<gblocks, 256, 0, stream>>>(bufB, Wf2, dis, bufA, N);
    k_agg<<<(N + 3) / 4, 256, 0, stream>>>(bufA, bufB, offs, cnt, dis, esrc, b2, N);
    // pool + fc
    k_pool<<<(N + 127) / 128, 128, 0, stream>>>(bufB, batch, pooled, gcnt, N);
    k_fc<<<NUM_GRAPHS, 128, 0, stream>>>(pooled, gcnt, fcW, fcb, out);
}

// Round 8
// 378.534 us; speedup vs baseline: 1.0533x; 1.0060x over previous
//
#include <hip/hip_runtime.h>
#include <hip/hip_bf16.h>
#include <math.h>

#define D 128
#define NUM_GRAPHS 64
#define CHUNK 8192          // edges per binning block
#define BUCK_SH 8           // bucket = col >> 8  (256 nodes per bucket)
#define BUCK_N 256

typedef __bf16 bf16x8 __attribute__((ext_vector_type(8)));
typedef __bf16 bf16x2 __attribute__((ext_vector_type(2)));
typedef float f32x4 __attribute__((ext_vector_type(4)));

// ---------------- generic scan helpers (for the bucket-chunk table) ----------------
__global__ void k_scan1(const int* __restrict__ in, int* __restrict__ outv,
                        int* __restrict__ bsum, int N) {
    __shared__ int lds[256];
    int t = threadIdx.x;
    int base = blockIdx.x * 1024 + t * 4;
    int v[4]; int local = 0;
#pragma unroll
    for (int j = 0; j < 4; j++) { v[j] = (base + j < N) ? in[base + j] : 0; local += v[j]; }
    lds[t] = local;
    __syncthreads();
    for (int off = 1; off < 256; off <<= 1) {
        int x = (t >= off) ? lds[t - off] : 0;
        __syncthreads();
        lds[t] += x;
        __syncthreads();
    }
    int excl = lds[t] - local;
    if (t == 255) bsum[blockIdx.x] = lds[255];
    int run = excl;
#pragma unroll
    for (int j = 0; j < 4; j++) { if (base + j < N) outv[base + j] = run; run += v[j]; }
}

__global__ void k_scan2(int* __restrict__ bsum, int nb) {
    __shared__ int lds[256];
    int t = threadIdx.x;
    int v = (t < nb) ? bsum[t] : 0;
    lds[t] = v;
    __syncthreads();
    for (int off = 1; off < 256; off <<= 1) {
        int x = (t >= off) ? lds[t - off] : 0;
        __syncthreads();
        lds[t] += x;
        __syncthreads();
    }
    if (t < nb) bsum[t] = lds[t] - v;
}

// ---------------- CSR build: two-level counting sort ----------------
__global__ void k_hist(const int* __restrict__ col, int* __restrict__ hist,
                       int nbuck, int nchunk, int E) {
    __shared__ int h[512];
    int tid = threadIdx.x;
    for (int b = tid; b < nbuck; b += 256) h[b] = 0;
    __syncthreads();
    int base = blockIdx.x * CHUNK;
    for (int i = tid; i < CHUNK; i += 256) {
        int e = base + i;
        if (e < E) atomicAdd(&h[col[e] >> BUCK_SH], 1);
    }
    __syncthreads();
    for (int b = tid; b < nbuck; b += 256) hist[b * nchunk + blockIdx.x] = h[b];
}

__global__ void k_bin(const int* __restrict__ ei, const int* __restrict__ histS,
                      const int* __restrict__ bsum2, int* __restrict__ bbuf,
                      int nbuck, int nchunk, int E) {
    __shared__ int cur[512];
    int tid = threadIdx.x;
    for (int b = tid; b < nbuck; b += 256) {
        int idx = b * nchunk + blockIdx.x;
        cur[b] = histS[idx] + bsum2[idx >> 10];
    }
    __syncthreads();
    int base = blockIdx.x * CHUNK;
    for (int i = tid; i < CHUNK; i += 256) {
        int e = base + i;
        if (e < E) {
            int r = ei[e], c = ei[E + e];
            int pos = atomicAdd(&cur[c >> BUCK_SH], 1);
            bbuf[pos] = r | ((c & (BUCK_N - 1)) << 17);   // src fits 17 bits (N < 131072)
        }
    }
}

// per-bucket exact CSR: LDS histogram + LDS scan + LDS cursors. No global atomics.
__global__ void k_place(const int* __restrict__ bbuf, const int* __restrict__ histS,
                        const int* __restrict__ bsum2, int* __restrict__ esrc,
                        int* __restrict__ cnt, int* __restrict__ offs,
                        float* __restrict__ dis,
                        int nbuck, int nchunk, int N, int E) {
    __shared__ int h[256];
    __shared__ int sc[256];
    __shared__ int cur[256];
    int b = blockIdx.x, tid = threadIdx.x;
    int i0 = b * nchunk;
    int start = histS[i0] + bsum2[i0 >> 10];
    int end = E;
    if (b + 1 < nbuck) { int i1 = (b + 1) * nchunk; end = histS[i1] + bsum2[i1 >> 10]; }
    h[tid] = 0;
    __syncthreads();
    for (int i = start + tid; i < end; i += 256) atomicAdd(&h[(bbuf[i] >> 17) & 255], 1);
    __syncthreads();
    int local = h[tid];
    sc[tid] = local;
    __syncthreads();
    for (int off = 1; off < 256; off <<= 1) {
        int xv = (tid >= off) ? sc[tid - off] : 0;
        __syncthreads();
        sc[tid] += xv;
        __syncthreads();
    }
    int excl = sc[tid] - local;
    cur[tid] = start + excl;
    int c = b * 256 + tid;
    if (c < N) {
        cnt[c]  = local;
        offs[c] = start + excl;
        dis[c]  = rsqrtf(1.0f + (float)local);   // deg includes self-loop
    }
    __syncthreads();
    for (int i = start + tid; i < end; i += 256) {
        int p = bbuf[i];
        int pos = atomicAdd(&cur[(p >> 17) & 255], 1);
        esrc[pos] = p & 0x1FFFF;
    }
}

// ---------------- W -> bf16 B-fragment pack (both weights; zeroes pooled/gcnt/done) ----------------
__global__ void k_prepW(const float* __restrict__ Wa, const float* __restrict__ Wb,
                        __bf16* __restrict__ WfA, __bf16* __restrict__ WfB,
                        float* __restrict__ pooled, float* __restrict__ gcnt,
                        int* __restrict__ done) {
    int gid = blockIdx.x * 256 + threadIdx.x;   // 0..32767
    if (gid < NUM_GRAPHS * D) pooled[gid] = 0.f;
    if (gid < NUM_GRAPHS) gcnt[gid] = 0.f;
    if (gid == 0) *done = 0;
    const float* W = (gid < 16384) ? Wa : Wb;
    __bf16* Wf = (gid < 16384) ? WfA : WfB;
    int idx = gid & 16383;
    int j = idx & 7, lane = (idx >> 3) & 63, kc = (idx >> 9) & 3, ft = idx >> 11;
    int k = kc * 32 + (lane >> 4) * 8 + j;
    int f = ft * 16 + (lane & 15);
    Wf[idx] = (__bf16)W[k * D + f];
}

// ---------------- MFMA GEMM: Y[N,128](bf16) = dis .* (X[N,128] @ W) ----------------
template <typename T>
__launch_bounds__(256)
__global__ void k_gemm(const T* __restrict__ X, const __bf16* __restrict__ Wfrag,
                       const float* __restrict__ dis, __bf16* __restrict__ Y, int N) {
    int tid = threadIdx.x;
    int w = tid >> 6, lane = tid & 63;
    int quad = lane >> 4, m = lane & 15;
    int nodeA = blockIdx.x * 64 + w * 16 + m;
    if (nodeA >= N) nodeA = N - 1;

    bf16x8 a[4];
#pragma unroll
    for (int kc = 0; kc < 4; kc++) {
        int kb = kc * 32 + quad * 8;
        if constexpr (sizeof(T) == 4) {
            f32x4 x0 = *(const f32x4*)(X + (size_t)nodeA * D + kb);
            f32x4 x1 = *(const f32x4*)(X + (size_t)nodeA * D + kb + 4);
#pragma unroll
            for (int j = 0; j < 4; j++) { a[kc][j] = (__bf16)x0[j]; a[kc][4 + j] = (__bf16)x1[j]; }
        } else {
            a[kc] = *(const bf16x8*)(X + (size_t)nodeA * D + kb);
        }
    }

    f32x4 d[8];
#pragma unroll
    for (int ft = 0; ft < 8; ft++) {
        d[ft] = (f32x4){0.f, 0.f, 0.f, 0.f};
#pragma unroll
        for (int kc = 0; kc < 4; kc++) {
            bf16x8 b = *(const bf16x8*)(Wfrag + (((ft << 2) | kc) * 64 + lane) * 8);
            d[ft] = __builtin_amdgcn_mfma_f32_16x16x32_bf16(a[kc], b, d[ft], 0, 0, 0);
        }
    }

#pragma unroll
    for (int r = 0; r < 4; r++) {
        int node = blockIdx.x * 64 + w * 16 + quad * 4 + r;
        if (node < N) {
            float dv = dis[node];
#pragma unroll
            for (int ft = 0; ft < 8; ft++)
                Y[(size_t)node * D + ft * 16 + m] = (__bf16)(d[ft][r] * dv);
        }
    }
}

// ---------------- CSR aggregation + bias + leaky ReLU (bf16 in/out) ----------------
// Hs prescaled by dis -> no per-edge weight. One wave per 8 consecutive nodes
// (longer-lived blocks -> higher sustained occupancy). Lane owns feats
// (2*lane, 2*lane+1). Edge meta preloaded 64-wide + shfl broadcast; x16 unroll.
__launch_bounds__(256)
__global__ void k_agg(const __bf16* __restrict__ Hs, __bf16* __restrict__ O,
                      const int* __restrict__ offs, const int* __restrict__ cnt,
                      const float* __restrict__ dis, const int* __restrict__ esrc,
                      const float* __restrict__ bias, int N) {
    int wave = (blockIdx.x * 256 + threadIdx.x) >> 6;
    int lane = threadIdx.x & 63;
    int node0 = wave * 8;
    float b0 = bias[lane * 2], b1 = bias[lane * 2 + 1];

    for (int nn = 0; nn < 8; nn++) {
        int node = node0 + nn;
        if (node >= N) return;
        int start = offs[node];
        int len = cnt[node];
        float di = dis[node];
        bf16x2 h = *(const bf16x2*)(Hs + (size_t)node * D + lane * 2);
        float acc0 = (float)h[0];            // self-loop term (already dis-scaled)
        float acc1 = (float)h[1];

        for (int k0 = 0; k0 < len; k0 += 64) {
            int mm = len - k0; if (mm > 64) mm = 64;
            int ep = esrc[start + k0 + (lane < mm ? lane : 0)];
            int j = 0;
            for (; j + 16 <= mm; j += 16) {
                int s[16]; bf16x2 hv[16];
#pragma unroll
                for (int u = 0; u < 16; u++) s[u] = __shfl(ep, j + u);
#pragma unroll
                for (int u = 0; u < 16; u++) hv[u] = *(const bf16x2*)(Hs + (size_t)s[u] * D + lane * 2);
#pragma unroll
                for (int u = 0; u < 16; u++) { acc0 += (float)hv[u][0]; acc1 += (float)hv[u][1]; }
            }
            for (; j + 4 <= mm; j += 4) {
                int s[4]; bf16x2 hv[4];
#pragma unroll
                for (int u = 0; u < 4; u++) s[u] = __shfl(ep, j + u);
#pragma unroll
                for (int u = 0; u < 4; u++) hv[u] = *(const bf16x2*)(Hs + (size_t)s[u] * D + lane * 2);
#pragma unroll
                for (int u = 0; u < 4; u++) { acc0 += (float)hv[u][0]; acc1 += (float)hv[u][1]; }
            }
            for (; j < mm; j++) {
                int s = __shfl(ep, j);
                bf16x2 hv = *(const bf16x2*)(Hs + (size_t)s * D + lane * 2);
                acc0 += (float)hv[0]; acc1 += (float)hv[1];
            }
        }

        acc0 = acc0 * di + b0;
        acc1 = acc1 * di + b1;
        acc0 = acc0 >= 0.f ? acc0 : 0.01f * acc0;
        acc1 = acc1 >= 0.f ? acc1 : 0.01f * acc1;
        bf16x2 o; o[0] = (__bf16)acc0; o[1] = (__bf16)acc1;
        *(bf16x2*)(O + (size_t)node * D + lane * 2) = o;
    }
}

// ---------------- pooling (bf16 in, fp32 accum) + fused FC via completion counter ----------------
__global__ void k_pool(const __bf16* __restrict__ H, const int* __restrict__ batch,
                       float* __restrict__ pooled, float* __restrict__ gcnt,
                       const float* __restrict__ fcW, const float* __restrict__ fcb,
                       float* __restrict__ out, int* __restrict__ done, int N) {
    __shared__ int lastflag;
    int f = threadIdx.x;                 // 0..127
    int n0 = blockIdx.x * 128;
    if (n0 < N) {
        int n1 = min(n0 + 128, N);
        int cur = batch[n0];
        float acc = 0.f; int run = 0;
        for (int n = n0; n < n1; n++) {
            int g = batch[n];            // uniform across block -> no divergence
            if (g != cur) {
                atomicAdd(&pooled[cur * D + f], acc);
                if (f == 0) atomicAdd(&gcnt[cur], (float)run);
                acc = 0.f; run = 0; cur = g;
            }
            acc += (float)H[(size_t)n * D + f];
            run++;
        }
        atomicAdd(&pooled[cur * D + f], acc);
        if (f == 0) atomicAdd(&gcnt[cur], (float)run);
    }
    __threadfence();                     // make this block's atomics visible
    __syncthreads();
    if (f == 0) lastflag = (atomicAdd(done, 1) == (int)gridDim.x - 1) ? 1 : 0;
    __syncthreads();
    if (lastflag) {
        __threadfence();                 // acquire all blocks' pooled sums
        if (f < NUM_GRAPHS) {
            float s = 0.f;
#pragma unroll 4
            for (int k = 0; k < D; k++) s += pooled[f * D + k] * fcW[k];
            out[f] = s / fmaxf(gcnt[f], 1.0f) + fcb[0];
        }
    }
}

extern "C" void kernel_launch(void* const* d_in, const int* in_sizes, int n_in,
                              void* d_out, int out_size, void* d_ws, size_t ws_size,
                              hipStream_t stream) {
    const float* x    = (const float*)d_in[0];
    const int*   ei   = (const int*)d_in[1];
    const int*   batch= (const int*)d_in[2];
    const float* W1   = (const float*)d_in[3];
    const float* b1   = (const float*)d_in[4];
    const float* W2   = (const float*)d_in[5];
    const float* b2   = (const float*)d_in[6];
    const float* fcW  = (const float*)d_in[7];
    const float* fcb  = (const float*)d_in[8];
    float* out = (float*)d_out;

    int N = in_sizes[0] / D;
    int E = in_sizes[1] / 2;

    int NBUCK  = (N + BUCK_N - 1) >> BUCK_SH;  // 391 for N=100000 (<=512)
    int NCHUNK = (E + CHUNK - 1) / CHUNK;      // 196 for E=1.6M
    int M = NBUCK * NCHUNK;                    // 76,636
    int mb = (M + 1023) / 1024;                // 75 (<=256)

    char* p = (char*)d_ws;
    auto alloc = [&](size_t bytes) { char* r = p; p += (bytes + 255) & ~(size_t)255; return r; };
    int*    cnt    = (int*)   alloc((size_t)N * 4);
    int*    offs   = (int*)   alloc((size_t)N * 4);
    int*    bsum2  = (int*)   alloc(256 * 4);
    float*  dis    = (float*) alloc((size_t)N * 4);
    int*    hist   = (int*)   alloc((size_t)M * 4);
    int*    histS  = (int*)   alloc((size_t)M * 4);
    int*    bbuf   = (int*)   alloc((size_t)E * 4);
    int*    esrc   = (int*)   alloc((size_t)E * 4);
    __bf16* bufA   = (__bf16*)alloc((size_t)N * D * 2);
    __bf16* bufB   = (__bf16*)alloc((size_t)N * D * 2);
    __bf16* Wf1    = (__bf16*)alloc((size_t)D * D * 2);
    __bf16* Wf2    = (__bf16*)alloc((size_t)D * D * 2);
    float*  pooled = (float*) alloc((size_t)NUM_GRAPHS * D * 4);
    float*  gcnt   = (float*) alloc((size_t)NUM_GRAPHS * 4);
    int*    done   = (int*)   alloc(256);

    // CSR build: hist -> scan -> bin -> per-bucket place (all-LDS cursors)
    k_hist <<<NCHUNK, 256, 0, stream>>>(ei + E, hist, NBUCK, NCHUNK, E);
    k_scan1<<<mb, 256, 0, stream>>>(hist, histS, bsum2, M);
    k_scan2<<<1, 256, 0, stream>>>(bsum2, mb);
    k_bin  <<<NCHUNK, 256, 0, stream>>>(ei, histS, bsum2, bbuf, NBUCK, NCHUNK, E);
    k_place<<<NBUCK, 256, 0, stream>>>(bbuf, histS, bsum2, esrc, cnt, offs, dis,
                                       NBUCK, NCHUNK, N, E);

    k_prepW<<<128, 256, 0, stream>>>(W1, W2, Wf1, Wf2, pooled, gcnt, done);

    int gblocks = (N + 63) / 64;
    int ablocks = (N + 31) / 32;     // 4 waves/block x 8 nodes/wave

    // layer 1 (GEMM output prescaled by dis)
    k_gemm<float><<<gblocks, 256, 0, stream>>>(x, Wf1, dis, bufA, N);
    k_agg<<<ablocks, 256, 0, stream>>>(bufA, bufB, offs, cnt, dis, esrc, b1, N);
    // layer 2
    k_gemm<__bf16><<<gblocks, 256, 0, stream>>>(bufB, Wf2, dis, bufA, N);
    k_agg<<<ablocks, 256, 0, stream>>>(bufA, bufB, offs, cnt, dis, esrc, b2, N);
    // pool + fused fc
    int pblocks = (N + 127) / 128;
    k_pool<<<pblocks, 128, 0, stream>>>(bufB, batch, pooled, gcnt, fcW, fcb, out, done, N);
}

// Round 9
// 355.542 us; speedup vs baseline: 1.1214x; 1.0647x over previous
//
#include <hip/hip_runtime.h>
#include <hip/hip_bf16.h>
#include <math.h>

#define D 128
#define NUM_GRAPHS 64
#define CHUNK 8192          // edges per binning block
#define BUCK_SH 8           // bucket = col >> 8  (256 nodes per bucket)
#define BUCK_N 256
#define PSLICE 8            // pooling blocks per graph

typedef __bf16 bf16x8 __attribute__((ext_vector_type(8)));
typedef __bf16 bf16x2 __attribute__((ext_vector_type(2)));
typedef float f32x4 __attribute__((ext_vector_type(4)));

// ---------------- generic scan helpers (for the bucket-chunk table) ----------------
__global__ void k_scan1(const int* __restrict__ in, int* __restrict__ outv,
                        int* __restrict__ bsum, int N) {
    __shared__ int lds[256];
    int t = threadIdx.x;
    int base = blockIdx.x * 1024 + t * 4;
    int v[4]; int local = 0;
#pragma unroll
    for (int j = 0; j < 4; j++) { v[j] = (base + j < N) ? in[base + j] : 0; local += v[j]; }
    lds[t] = local;
    __syncthreads();
    for (int off = 1; off < 256; off <<= 1) {
        int x = (t >= off) ? lds[t - off] : 0;
        __syncthreads();
        lds[t] += x;
        __syncthreads();
    }
    int excl = lds[t] - local;
    if (t == 255) bsum[blockIdx.x] = lds[255];
    int run = excl;
#pragma unroll
    for (int j = 0; j < 4; j++) { if (base + j < N) outv[base + j] = run; run += v[j]; }
}

__global__ void k_scan2(int* __restrict__ bsum, int nb) {
    __shared__ int lds[256];
    int t = threadIdx.x;
    int v = (t < nb) ? bsum[t] : 0;
    lds[t] = v;
    __syncthreads();
    for (int off = 1; off < 256; off <<= 1) {
        int x = (t >= off) ? lds[t - off] : 0;
        __syncthreads();
        lds[t] += x;
        __syncthreads();
    }
    if (t < nb) bsum[t] = lds[t] - v;
}

// ---------------- CSR build: two-level counting sort ----------------
__global__ void k_hist(const int* __restrict__ col, int* __restrict__ hist,
                       int nbuck, int nchunk, int E) {
    __shared__ int h[512];
    int tid = threadIdx.x;
    for (int b = tid; b < nbuck; b += 256) h[b] = 0;
    __syncthreads();
    int base = blockIdx.x * CHUNK;
    for (int i = tid; i < CHUNK; i += 256) {
        int e = base + i;
        if (e < E) atomicAdd(&h[col[e] >> BUCK_SH], 1);
    }
    __syncthreads();
    for (int b = tid; b < nbuck; b += 256) hist[b * nchunk + blockIdx.x] = h[b];
}

__global__ void k_bin(const int* __restrict__ ei, const int* __restrict__ histS,
                      const int* __restrict__ bsum2, int* __restrict__ bbuf,
                      int nbuck, int nchunk, int E) {
    __shared__ int cur[512];
    int tid = threadIdx.x;
    for (int b = tid; b < nbuck; b += 256) {
        int idx = b * nchunk + blockIdx.x;
        cur[b] = histS[idx] + bsum2[idx >> 10];
    }
    __syncthreads();
    int base = blockIdx.x * CHUNK;
    for (int i = tid; i < CHUNK; i += 256) {
        int e = base + i;
        if (e < E) {
            int r = ei[e], c = ei[E + e];
            int pos = atomicAdd(&cur[c >> BUCK_SH], 1);
            bbuf[pos] = r | ((c & (BUCK_N - 1)) << 17);   // src fits 17 bits (N < 131072)
        }
    }
}

// per-bucket exact CSR: LDS histogram + LDS scan + LDS cursors. No global atomics.
__global__ void k_place(const int* __restrict__ bbuf, const int* __restrict__ histS,
                        const int* __restrict__ bsum2, int* __restrict__ esrc,
                        int* __restrict__ cnt, int* __restrict__ offs,
                        float* __restrict__ dis,
                        int nbuck, int nchunk, int N, int E) {
    __shared__ int h[256];
    __shared__ int sc[256];
    __shared__ int cur[256];
    int b = blockIdx.x, tid = threadIdx.x;
    int i0 = b * nchunk;
    int start = histS[i0] + bsum2[i0 >> 10];
    int end = E;
    if (b + 1 < nbuck) { int i1 = (b + 1) * nchunk; end = histS[i1] + bsum2[i1 >> 10]; }
    h[tid] = 0;
    __syncthreads();
    for (int i = start + tid; i < end; i += 256) atomicAdd(&h[(bbuf[i] >> 17) & 255], 1);
    __syncthreads();
    int local = h[tid];
    sc[tid] = local;
    __syncthreads();
    for (int off = 1; off < 256; off <<= 1) {
        int xv = (tid >= off) ? sc[tid - off] : 0;
        __syncthreads();
        sc[tid] += xv;
        __syncthreads();
    }
    int excl = sc[tid] - local;
    cur[tid] = start + excl;
    int c = b * 256 + tid;
    if (c < N) {
        cnt[c]  = local;
        offs[c] = start + excl;
        dis[c]  = rsqrtf(1.0f + (float)local);   // deg includes self-loop
    }
    __syncthreads();
    for (int i = start + tid; i < end; i += 256) {
        int p = bbuf[i];
        int pos = atomicAdd(&cur[(p >> 17) & 255], 1);
        esrc[pos] = p & 0x1FFFF;
    }
}

// ---------------- W -> bf16 B-fragment pack; zero pooled/done; graph boundaries ----------------
__global__ void k_prepW(const float* __restrict__ Wa, const float* __restrict__ Wb,
                        __bf16* __restrict__ WfA, __bf16* __restrict__ WfB,
                        float* __restrict__ pooled, int* __restrict__ done,
                        const int* __restrict__ batch, int* __restrict__ gstart, int N) {
    int gid = blockIdx.x * 256 + threadIdx.x;   // 0..32767
    if (gid < NUM_GRAPHS * D) pooled[gid] = 0.f;
    if (gid == 0) *done = 0;
    if (gid >= 16384 && gid <= 16384 + NUM_GRAPHS) {   // 65 threads do binary search
        int g = gid - 16384;
        int lo = 0, hi = N;
        while (lo < hi) { int mid = (lo + hi) >> 1; if (batch[mid] < g) lo = mid + 1; else hi = mid; }
        gstart[g] = lo;
    }
    const float* W = (gid < 16384) ? Wa : Wb;
    __bf16* Wf = (gid < 16384) ? WfA : WfB;
    int idx = gid & 16383;
    int j = idx & 7, lane = (idx >> 3) & 63, kc = (idx >> 9) & 3, ft = idx >> 11;
    int k = kc * 32 + (lane >> 4) * 8 + j;
    int f = ft * 16 + (lane & 15);
    Wf[idx] = (__bf16)W[k * D + f];
}

// ---------------- MFMA GEMM: Y[N,128](bf16) = dis .* (X[N,128] @ W) ----------------
template <typename T>
__launch_bounds__(256)
__global__ void k_gemm(const T* __restrict__ X, const __bf16* __restrict__ Wfrag,
                       const float* __restrict__ dis, __bf16* __restrict__ Y, int N) {
    int tid = threadIdx.x;
    int w = tid >> 6, lane = tid & 63;
    int quad = lane >> 4, m = lane & 15;
    int nodeA = blockIdx.x * 64 + w * 16 + m;
    if (nodeA >= N) nodeA = N - 1;

    bf16x8 a[4];
#pragma unroll
    for (int kc = 0; kc < 4; kc++) {
        int kb = kc * 32 + quad * 8;
        if constexpr (sizeof(T) == 4) {
            f32x4 x0 = *(const f32x4*)(X + (size_t)nodeA * D + kb);
            f32x4 x1 = *(const f32x4*)(X + (size_t)nodeA * D + kb + 4);
#pragma unroll
            for (int j = 0; j < 4; j++) { a[kc][j] = (__bf16)x0[j]; a[kc][4 + j] = (__bf16)x1[j]; }
        } else {
            a[kc] = *(const bf16x8*)(X + (size_t)nodeA * D + kb);
        }
    }

    f32x4 d[8];
#pragma unroll
    for (int ft = 0; ft < 8; ft++) {
        d[ft] = (f32x4){0.f, 0.f, 0.f, 0.f};
#pragma unroll
        for (int kc = 0; kc < 4; kc++) {
            bf16x8 b = *(const bf16x8*)(Wfrag + (((ft << 2) | kc) * 64 + lane) * 8);
            d[ft] = __builtin_amdgcn_mfma_f32_16x16x32_bf16(a[kc], b, d[ft], 0, 0, 0);
        }
    }

#pragma unroll
    for (int r = 0; r < 4; r++) {
        int node = blockIdx.x * 64 + w * 16 + quad * 4 + r;
        if (node < N) {
            float dv = dis[node];
#pragma unroll
            for (int ft = 0; ft < 8; ft++)
                Y[(size_t)node * D + ft * 16 + m] = (__bf16)(d[ft][r] * dv);
        }
    }
}

// ---------------- CSR aggregation + bias + leaky ReLU (bf16 in/out) ----------------
__launch_bounds__(256)
__global__ void k_agg(const __bf16* __restrict__ Hs, __bf16* __restrict__ O,
                      const int* __restrict__ offs, const int* __restrict__ cnt,
                      const float* __restrict__ dis, const int* __restrict__ esrc,
                      const float* __restrict__ bias, int N) {
    int wave = (blockIdx.x * 256 + threadIdx.x) >> 6;
    int lane = threadIdx.x & 63;
    int node0 = wave * 8;
    float b0 = bias[lane * 2], b1 = bias[lane * 2 + 1];

    for (int nn = 0; nn < 8; nn++) {
        int node = node0 + nn;
        if (node >= N) return;
        int start = offs[node];
        int len = cnt[node];
        float di = dis[node];
        bf16x2 h = *(const bf16x2*)(Hs + (size_t)node * D + lane * 2);
        float acc0 = (float)h[0];            // self-loop term (already dis-scaled)
        float acc1 = (float)h[1];

        for (int k0 = 0; k0 < len; k0 += 64) {
            int mm = len - k0; if (mm > 64) mm = 64;
            int ep = esrc[start + k0 + (lane < mm ? lane : 0)];
            int j = 0;
            for (; j + 16 <= mm; j += 16) {
                int s[16]; bf16x2 hv[16];
#pragma unroll
                for (int u = 0; u < 16; u++) s[u] = __shfl(ep, j + u);
#pragma unroll
                for (int u = 0; u < 16; u++) hv[u] = *(const bf16x2*)(Hs + (size_t)s[u] * D + lane * 2);
#pragma unroll
                for (int u = 0; u < 16; u++) { acc0 += (float)hv[u][0]; acc1 += (float)hv[u][1]; }
            }
            for (; j + 4 <= mm; j += 4) {
                int s[4]; bf16x2 hv[4];
#pragma unroll
                for (int u = 0; u < 4; u++) s[u] = __shfl(ep, j + u);
#pragma unroll
                for (int u = 0; u < 4; u++) hv[u] = *(const bf16x2*)(Hs + (size_t)s[u] * D + lane * 2);
#pragma unroll
                for (int u = 0; u < 4; u++) { acc0 += (float)hv[u][0]; acc1 += (float)hv[u][1]; }
            }
            for (; j < mm; j++) {
                int s = __shfl(ep, j);
                bf16x2 hv = *(const bf16x2*)(Hs + (size_t)s * D + lane * 2);
                acc0 += (float)hv[0]; acc1 += (float)hv[1];
            }
        }

        acc0 = acc0 * di + b0;
        acc1 = acc1 * di + b1;
        acc0 = acc0 >= 0.f ? acc0 : 0.01f * acc0;
        acc1 = acc1 >= 0.f ? acc1 : 0.01f * acc1;
        bf16x2 o; o[0] = (__bf16)acc0; o[1] = (__bf16)acc1;
        *(bf16x2*)(O + (size_t)node * D + lane * 2) = o;
    }
}

// ---------------- pooling: per-graph-slice vectorized reduction + fused FC ----------------
// Grid = NUM_GRAPHS * PSLICE. Thread t: feat-block t&15 (bf16x8), row-group t>>4
// -> each iteration the block reads 16 rows x 256 B = 4 KB fully coalesced.
__launch_bounds__(256)
__global__ void k_pool(const __bf16* __restrict__ H, const int* __restrict__ gstart,
                       float* __restrict__ pooled,
                       const float* __restrict__ fcW, const float* __restrict__ fcb,
                       float* __restrict__ out, int* __restrict__ done) {
    __shared__ float sdata[256 * 9];
    __shared__ int lastflag;
    int g = blockIdx.x / PSLICE;
    int slice = blockIdx.x - g * PSLICE;
    int gs = gstart[g], ge = gstart[g + 1];
    int cg = ge - gs;
    int r0 = gs + (int)((long long)cg * slice / PSLICE);
    int r1 = gs + (int)((long long)cg * (slice + 1) / PSLICE);
    int t = threadIdx.x;
    int rg = t >> 4, fb = t & 15;

    float acc[8];
#pragma unroll
    for (int j = 0; j < 8; j++) acc[j] = 0.f;
    for (int r = r0 + rg; r < r1; r += 16) {
        bf16x8 v = *(const bf16x8*)(H + (size_t)r * D + fb * 8);
#pragma unroll
        for (int j = 0; j < 8; j++) acc[j] += (float)v[j];
    }
#pragma unroll
    for (int j = 0; j < 8; j++) sdata[t * 9 + j] = acc[j];
    __syncthreads();
#pragma unroll
    for (int s = 128; s >= 16; s >>= 1) {
        if (t < s) {
#pragma unroll
            for (int j = 0; j < 8; j++) sdata[t * 9 + j] += sdata[(t + s) * 9 + j];
        }
        __syncthreads();
    }
    if (t < 16) {
#pragma unroll
        for (int j = 0; j < 8; j++) atomicAdd(&pooled[g * D + t * 8 + j], sdata[t * 9 + j]);
    }
    __threadfence();
    __syncthreads();
    if (t == 0) lastflag = (atomicAdd(done, 1) == (int)gridDim.x - 1) ? 1 : 0;
    __syncthreads();
    if (lastflag) {
        __threadfence();
        if (t < NUM_GRAPHS) {
            float s = 0.f;
#pragma unroll 4
            for (int k = 0; k < D; k++) s += pooled[t * D + k] * fcW[k];
            float c = (float)(gstart[t + 1] - gstart[t]);
            out[t] = s / fmaxf(c, 1.0f) + fcb[0];
        }
    }
}

extern "C" void kernel_launch(void* const* d_in, const int* in_sizes, int n_in,
                              void* d_out, int out_size, void* d_ws, size_t ws_size,
                              hipStream_t stream) {
    const float* x    = (const float*)d_in[0];
    const int*   ei   = (const int*)d_in[1];
    const int*   batch= (const int*)d_in[2];
    const float* W1   = (const float*)d_in[3];
    const float* b1   = (const float*)d_in[4];
    const float* W2   = (const float*)d_in[5];
    const float* b2   = (const float*)d_in[6];
    const float* fcW  = (const float*)d_in[7];
    const float* fcb  = (const float*)d_in[8];
    float* out = (float*)d_out;

    int N = in_sizes[0] / D;
    int E = in_sizes[1] / 2;

    int NBUCK  = (N + BUCK_N - 1) >> BUCK_SH;  // 391 for N=100000 (<=512)
    int NCHUNK = (E + CHUNK - 1) / CHUNK;      // 196 for E=1.6M
    int M = NBUCK * NCHUNK;                    // 76,636
    int mb = (M + 1023) / 1024;                // 75 (<=256)

    char* p = (char*)d_ws;
    auto alloc = [&](size_t bytes) { char* r = p; p += (bytes + 255) & ~(size_t)255; return r; };
    int*    cnt    = (int*)   alloc((size_t)N * 4);
    int*    offs   = (int*)   alloc((size_t)N * 4);
    int*    bsum2  = (int*)   alloc(256 * 4);
    float*  dis    = (float*) alloc((size_t)N * 4);
    int*    hist   = (int*)   alloc((size_t)M * 4);
    int*    histS  = (int*)   alloc((size_t)M * 4);
    int*    bbuf   = (int*)   alloc((size_t)E * 4);
    int*    esrc   = (int*)   alloc((size_t)E * 4);
    __bf16* bufA   = (__bf16*)alloc((size_t)N * D * 2);
    __bf16* bufB   = (__bf16*)alloc((size_t)N * D * 2);
    __bf16* Wf1    = (__bf16*)alloc((size_t)D * D * 2);
    __bf16* Wf2    = (__bf16*)alloc((size_t)D * D * 2);
    float*  pooled = (float*) alloc((size_t)NUM_GRAPHS * D * 4);
    int*    gstart = (int*)   alloc((NUM_GRAPHS + 1) * 4);
    int*    done   = (int*)   alloc(256);

    // CSR build: hist -> scan -> bin -> per-bucket place (all-LDS cursors)
    k_hist <<<NCHUNK, 256, 0, stream>>>(ei + E, hist, NBUCK, NCHUNK, E);
    k_scan1<<<mb, 256, 0, stream>>>(hist, histS, bsum2, M);
    k_scan2<<<1, 256, 0, stream>>>(bsum2, mb);
    k_bin  <<<NCHUNK, 256, 0, stream>>>(ei, histS, bsum2, bbuf, NBUCK, NCHUNK, E);
    k_place<<<NBUCK, 256, 0, stream>>>(bbuf, histS, bsum2, esrc, cnt, offs, dis,
                                       NBUCK, NCHUNK, N, E);

    k_prepW<<<129, 256, 0, stream>>>(W1, W2, Wf1, Wf2, pooled, done, batch, gstart, N);

    int gblocks = (N + 63) / 64;
    int ablocks = (N + 31) / 32;     // 4 waves/block x 8 nodes/wave

    // layer 1 (GEMM output prescaled by dis)
    k_gemm<float><<<gblocks, 256, 0, stream>>>(x, Wf1, dis, bufA, N);
    k_agg<<<ablocks, 256, 0, stream>>>(bufA, bufB, offs, cnt, dis, esrc, b1, N);
    // layer 2
    k_gemm<__bf16><<<gblocks, 256, 0, stream>>>(bufB, Wf2, dis, bufA, N);
    k_agg<<<ablocks, 256, 0, stream>>>(bufA, bufB, offs, cnt, dis, esrc, b2, N);
    // pool (vectorized, per-graph slices) + fused fc
    k_pool<<<NUM_GRAPHS * PSLICE, 256, 0, stream>>>(bufB, gstart, pooled, fcW, fcb, out, done);
}